// Round 11
// baseline (344.603 us; speedup 1.0000x reference)
//
#include <hip/hip_runtime.h>
#include <hip/hip_bf16.h>

#define B_SZ  64
#define N_SZ  512
#define K_SZ  16
#define EMB   128
#define R_TOT (B_SZ * N_SZ)   // 32768 rows
#define REPS  12

typedef __attribute__((ext_vector_type(8))) short bf16x8;
typedef __attribute__((ext_vector_type(4))) float f32x4;

// XOR-swizzled u16 index into a [*][128]-u16 LDS tile (16B-unit granularity).
#define SWZ(row, col) ((((row) << 7)) + ((((col) >> 3) ^ ((row) & 15)) << 3) + ((col) & 7))

static __device__ __forceinline__ unsigned short f2bf(float x) {
    __hip_bfloat16 h = __float2bfloat16(x);   // RNE
    return *reinterpret_cast<unsigned short*>(&h);
}
static __device__ __forceinline__ float bf2f(unsigned short u) {
    union { unsigned int u32; float f; } c; c.u32 = ((unsigned int)u) << 16; return c.f;
}

// Opaque pointer pass-through: defeats LICM/CSE across probe rep-loops (rule #17).
template <typename T>
static __device__ __forceinline__ const T* launder(const T* p) {
    unsigned long long v = (unsigned long long)p;
    asm volatile("" : "+v"(v));
    return (const T*)v;
}

// ============================ REAL KERNELS (identical to R10) ============================

__global__ __launch_bounds__(256) void dual_gemm(const float* __restrict__ word,
                                                 const float* __restrict__ W_enc,
                                                 const float* __restrict__ bias,
                                                 unsigned short* __restrict__ Xb,
                                                 unsigned short* __restrict__ Yb,
                                                 float* __restrict__ out)
{
    __shared__ unsigned short sA0[64 * EMB];   // 16 KB, bf16(word) tile, swizzled
    __shared__ unsigned short sA1[64 * EMB];   // 16 KB, relu(X) tile, swizzled
    const int tid = threadIdx.x;

    const int bid    = blockIdx.x;
    const int xcd    = bid & 7;
    const int j      = bid >> 3;
    const int b      = xcd + 8 * (j & 7);
    const int rchunk = j >> 3;
    const int block_row = b * N_SZ + rchunk * 64;

    if (bid < 32) out[bid * 256 + tid] = 0.f;

    for (int i = tid; i < 2048; i += 256) {
        int r = i >> 5, c4 = i & 31;
        float4 v = ((const float4*)(word + (size_t)(block_row + r) * EMB))[c4];
        unsigned short o[4] = { f2bf(v.x), f2bf(v.y), f2bf(v.z), f2bf(v.w) };
        *(uint2*)&sA0[SWZ(r, c4 * 4)] = *(uint2*)o;
    }

    const int lane  = tid & 63;
    const int w     = tid >> 6;
    const int l15   = lane & 15;
    const int g     = lane >> 4;
    const int ncol0 = w * 32;

    bf16x8 bfr[2][4];
    #pragma unroll
    for (int nb = 0; nb < 2; ++nb) {
        const int col = ncol0 + nb * 16 + l15;
        #pragma unroll
        for (int ks = 0; ks < 4; ++ks) {
            unsigned short t[8];
            #pragma unroll
            for (int jj = 0; jj < 8; ++jj)
                t[jj] = f2bf(W_enc[(size_t)(ks * 32 + g * 8 + jj) * EMB + col]);
            bfr[nb][ks] = *(bf16x8*)t;
        }
    }

    f32x4 acc[4][2];
    #pragma unroll
    for (int mb = 0; mb < 4; ++mb)
        #pragma unroll
        for (int nb = 0; nb < 2; ++nb)
            acc[mb][nb] = (f32x4){0.f, 0.f, 0.f, 0.f};

    __syncthreads();

    #pragma unroll
    for (int ks = 0; ks < 4; ++ks) {
        bf16x8 a[4];
        #pragma unroll
        for (int mb = 0; mb < 4; ++mb)
            a[mb] = *(const bf16x8*)&sA0[SWZ(mb * 16 + l15, ks * 32 + g * 8)];
        #pragma unroll
        for (int mb = 0; mb < 4; ++mb)
            #pragma unroll
            for (int nb = 0; nb < 2; ++nb)
                acc[mb][nb] = __builtin_amdgcn_mfma_f32_16x16x32_bf16(a[mb], bfr[nb][ks], acc[mb][nb], 0, 0, 0);
    }

    bf16x8 bfr2[2][4];
    #pragma unroll
    for (int nb = 0; nb < 2; ++nb) {
        const int col = ncol0 + nb * 16 + l15;
        #pragma unroll
        for (int ks = 0; ks < 4; ++ks) {
            unsigned short t[8];
            #pragma unroll
            for (int jj = 0; jj < 8; ++jj)
                t[jj] = f2bf(W_enc[(size_t)(128 + ks * 32 + g * 8 + jj) * EMB + col]);
            bfr2[nb][ks] = *(bf16x8*)t;
        }
    }

    #pragma unroll
    for (int mb = 0; mb < 4; ++mb) {
        #pragma unroll
        for (int nb = 0; nb < 2; ++nb) {
            const int col = ncol0 + nb * 16 + l15;
            const float bv = bias[col];
            #pragma unroll
            for (int r = 0; r < 4; ++r) {
                const int row_l = mb * 16 + g * 4 + r;
                float x = acc[mb][nb][r] + bv;
                Xb[(size_t)(block_row + row_l) * EMB + col] = f2bf(x);
                sA1[SWZ(row_l, col)] = f2bf(fmaxf(x, 0.f));
            }
            acc[mb][nb] = (f32x4){0.f, 0.f, 0.f, 0.f};
        }
    }
    __syncthreads();

    #pragma unroll
    for (int ks = 0; ks < 4; ++ks) {
        bf16x8 a[4];
        #pragma unroll
        for (int mb = 0; mb < 4; ++mb)
            a[mb] = *(const bf16x8*)&sA1[SWZ(mb * 16 + l15, ks * 32 + g * 8)];
        #pragma unroll
        for (int mb = 0; mb < 4; ++mb)
            #pragma unroll
            for (int nb = 0; nb < 2; ++nb)
                acc[mb][nb] = __builtin_amdgcn_mfma_f32_16x16x32_bf16(a[mb], bfr2[nb][ks], acc[mb][nb], 0, 0, 0);
    }
    #pragma unroll
    for (int mb = 0; mb < 4; ++mb)
        #pragma unroll
        for (int nb = 0; nb < 2; ++nb) {
            const int col = ncol0 + nb * 16 + l15;
            #pragma unroll
            for (int r = 0; r < 4; ++r) {
                const int row_l = mb * 16 + g * 4 + r;
                Yb[(size_t)(block_row + row_l) * EMB + col] = f2bf(acc[mb][nb][r]);
            }
        }
}

__global__ __launch_bounds__(256) void gather_pool_w2(const unsigned short* __restrict__ Xb,
                                                      const unsigned short* __restrict__ Yb,
                                                      const int*   __restrict__ nbr,
                                                      const float* __restrict__ mask,
                                                      const float* __restrict__ W2,
                                                      float* __restrict__ out)
{
    const int bid   = blockIdx.x;
    const int xcd   = bid & 7;
    const int rest  = bid >> 3;
    const int chunk = rest & 15;
    const int b     = (rest >> 4) * 8 + xcd;
    const int g     = threadIdx.x >> 6;
    const int lane  = threadIdx.x & 63;
    const int e0    = lane * 2;
    const unsigned short* Yb_b = Yb + (size_t)b * N_SZ * EMB;

    float s0 = 0.f, s1 = 0.f;
    for (int nn = 0; nn < 8; ++nn) {
        const int n = chunk * 32 + g * 8 + nn;
        const long base = (long)b * N_SZ + n;
        const int* idx = nbr + base * K_SZ;
        int id[K_SZ];
        #pragma unroll
        for (int k = 0; k < K_SZ; ++k) id[k] = idx[k];
        float a0 = 0.f, a1 = 0.f;
        #pragma unroll
        for (int k = 0; k < K_SZ; ++k) {
            unsigned int v = *(const unsigned int*)(Yb_b + (size_t)id[k] * EMB + e0);
            a0 += bf2f((unsigned short)v);
            a1 += bf2f((unsigned short)(v >> 16));
        }
        unsigned int xv = *(const unsigned int*)(Xb + base * EMB + e0);
        const float m = mask[base];
        s0 += fmaxf(bf2f((unsigned short)xv)         + a0 * 0.0625f, 0.f) * m;
        s1 += fmaxf(bf2f((unsigned short)(xv >> 16)) + a1 * 0.0625f, 0.f) * m;
    }

    __shared__ float sred[4][EMB];
    sred[g][e0]     = s0;
    sred[g][e0 + 1] = s1;
    __syncthreads();
    const int t = threadIdx.x;
    if (t < EMB)
        sred[0][t] = sred[0][t] + sred[1][t] + sred[2][t] + sred[3][t];
    __syncthreads();

    if (t < EMB) {
        float r = 0.f;
        #pragma unroll 8
        for (int f = 0; f < EMB; ++f) r += sred[0][f] * W2[f * EMB + t];
        atomicAdd(&out[b * EMB + t], r);
    }
}

// ============================ PROBE KERNELS (instrumentation only) ============================
// Same work as the real kernels, REPS× in an internal loop, outputs to dummy ws
// buffers. Input pointers laundered per rep so the compiler re-executes every rep.

__global__ __launch_bounds__(256) void probe_dual(const float* __restrict__ word_in,
                                                  const float* __restrict__ Wenc_in,
                                                  const float* __restrict__ bias,
                                                  unsigned short* __restrict__ Xp,
                                                  unsigned short* __restrict__ Yp)
{
    __shared__ unsigned short sA0[64 * EMB];
    __shared__ unsigned short sA1[64 * EMB];
    const int tid = threadIdx.x;
    const int bid    = blockIdx.x;
    const int xcd    = bid & 7;
    const int j      = bid >> 3;
    const int b      = xcd + 8 * (j & 7);
    const int rchunk = j >> 3;
    const int block_row = b * N_SZ + rchunk * 64;

    const int lane  = tid & 63;
    const int w     = tid >> 6;
    const int l15   = lane & 15;
    const int g     = lane >> 4;
    const int ncol0 = w * 32;

    for (int rep = 0; rep < REPS; ++rep) {
        const float* word  = launder(word_in);
        const float* W_enc = launder(Wenc_in);

        for (int i = tid; i < 2048; i += 256) {
            int r = i >> 5, c4 = i & 31;
            float4 v = ((const float4*)(word + (size_t)(block_row + r) * EMB))[c4];
            unsigned short o[4] = { f2bf(v.x), f2bf(v.y), f2bf(v.z), f2bf(v.w) };
            *(uint2*)&sA0[SWZ(r, c4 * 4)] = *(uint2*)o;
        }

        bf16x8 bfr[2][4];
        #pragma unroll
        for (int nb = 0; nb < 2; ++nb) {
            const int col = ncol0 + nb * 16 + l15;
            #pragma unroll
            for (int ks = 0; ks < 4; ++ks) {
                unsigned short t[8];
                #pragma unroll
                for (int jj = 0; jj < 8; ++jj)
                    t[jj] = f2bf(W_enc[(size_t)(ks * 32 + g * 8 + jj) * EMB + col]);
                bfr[nb][ks] = *(bf16x8*)t;
            }
        }

        f32x4 acc[4][2];
        #pragma unroll
        for (int mb = 0; mb < 4; ++mb)
            #pragma unroll
            for (int nb = 0; nb < 2; ++nb)
                acc[mb][nb] = (f32x4){0.f, 0.f, 0.f, 0.f};

        __syncthreads();

        #pragma unroll
        for (int ks = 0; ks < 4; ++ks) {
            bf16x8 a[4];
            #pragma unroll
            for (int mb = 0; mb < 4; ++mb)
                a[mb] = *(const bf16x8*)&sA0[SWZ(mb * 16 + l15, ks * 32 + g * 8)];
            #pragma unroll
            for (int mb = 0; mb < 4; ++mb)
                #pragma unroll
                for (int nb = 0; nb < 2; ++nb)
                    acc[mb][nb] = __builtin_amdgcn_mfma_f32_16x16x32_bf16(a[mb], bfr[nb][ks], acc[mb][nb], 0, 0, 0);
        }

        bf16x8 bfr2[2][4];
        #pragma unroll
        for (int nb = 0; nb < 2; ++nb) {
            const int col = ncol0 + nb * 16 + l15;
            #pragma unroll
            for (int ks = 0; ks < 4; ++ks) {
                unsigned short t[8];
                #pragma unroll
                for (int jj = 0; jj < 8; ++jj)
                    t[jj] = f2bf(W_enc[(size_t)(128 + ks * 32 + g * 8 + jj) * EMB + col]);
                bfr2[nb][ks] = *(bf16x8*)t;
            }
        }

        #pragma unroll
        for (int mb = 0; mb < 4; ++mb) {
            #pragma unroll
            for (int nb = 0; nb < 2; ++nb) {
                const int col = ncol0 + nb * 16 + l15;
                const float bv = bias[col];
                #pragma unroll
                for (int r = 0; r < 4; ++r) {
                    const int row_l = mb * 16 + g * 4 + r;
                    float x = acc[mb][nb][r] + bv;
                    Xp[(size_t)(block_row + row_l) * EMB + col] = f2bf(x);
                    sA1[SWZ(row_l, col)] = f2bf(fmaxf(x, 0.f));
                }
                acc[mb][nb] = (f32x4){0.f, 0.f, 0.f, 0.f};
            }
        }
        __syncthreads();

        #pragma unroll
        for (int ks = 0; ks < 4; ++ks) {
            bf16x8 a[4];
            #pragma unroll
            for (int mb = 0; mb < 4; ++mb)
                a[mb] = *(const bf16x8*)&sA1[SWZ(mb * 16 + l15, ks * 32 + g * 8)];
            #pragma unroll
            for (int mb = 0; mb < 4; ++mb)
                #pragma unroll
                for (int nb = 0; nb < 2; ++nb)
                    acc[mb][nb] = __builtin_amdgcn_mfma_f32_16x16x32_bf16(a[mb], bfr2[nb][ks], acc[mb][nb], 0, 0, 0);
        }
        #pragma unroll
        for (int mb = 0; mb < 4; ++mb)
            #pragma unroll
            for (int nb = 0; nb < 2; ++nb) {
                const int col = ncol0 + nb * 16 + l15;
                #pragma unroll
                for (int r = 0; r < 4; ++r) {
                    const int row_l = mb * 16 + g * 4 + r;
                    Yp[(size_t)(block_row + row_l) * EMB + col] = f2bf(acc[mb][nb][r]);
                }
            }
        __syncthreads();   // sA0 restage next rep vs this rep's sA1 readers
    }
}

__global__ __launch_bounds__(256) void probe_gather(const unsigned short* __restrict__ Xb_in,
                                                    const unsigned short* __restrict__ Yb_in,
                                                    const int*   __restrict__ nbr_in,
                                                    const float* __restrict__ mask,
                                                    const float* __restrict__ W2,
                                                    float* __restrict__ dummy)
{
    const int bid   = blockIdx.x;
    const int xcd   = bid & 7;
    const int rest  = bid >> 3;
    const int chunk = rest & 15;
    const int b     = (rest >> 4) * 8 + xcd;
    const int g     = threadIdx.x >> 6;
    const int lane  = threadIdx.x & 63;
    const int e0    = lane * 2;
    __shared__ float sred[4][EMB];

    for (int rep = 0; rep < REPS; ++rep) {
        const unsigned short* Xb = launder(Xb_in);
        const unsigned short* Yb = launder(Yb_in);
        const int* nbr = launder(nbr_in);
        const unsigned short* Yb_b = Yb + (size_t)b * N_SZ * EMB;

        float s0 = 0.f, s1 = 0.f;
        for (int nn = 0; nn < 8; ++nn) {
            const int n = chunk * 32 + g * 8 + nn;
            const long base = (long)b * N_SZ + n;
            const int* idx = nbr + base * K_SZ;
            int id[K_SZ];
            #pragma unroll
            for (int k = 0; k < K_SZ; ++k) id[k] = idx[k];
            float a0 = 0.f, a1 = 0.f;
            #pragma unroll
            for (int k = 0; k < K_SZ; ++k) {
                unsigned int v = *(const unsigned int*)(Yb_b + (size_t)id[k] * EMB + e0);
                a0 += bf2f((unsigned short)v);
                a1 += bf2f((unsigned short)(v >> 16));
            }
            unsigned int xv = *(const unsigned int*)(Xb + base * EMB + e0);
            const float m = mask[base];
            s0 += fmaxf(bf2f((unsigned short)xv)         + a0 * 0.0625f, 0.f) * m;
            s1 += fmaxf(bf2f((unsigned short)(xv >> 16)) + a1 * 0.0625f, 0.f) * m;
        }

        sred[g][e0]     = s0;
        sred[g][e0 + 1] = s1;
        __syncthreads();
        const int t = threadIdx.x;
        if (t < EMB)
            sred[0][t] = sred[0][t] + sred[1][t] + sred[2][t] + sred[3][t];
        __syncthreads();
        if (t < EMB) {
            float r = 0.f;
            #pragma unroll 8
            for (int f = 0; f < EMB; ++f) r += sred[0][f] * W2[f * EMB + t];
            dummy[(size_t)bid * EMB + t] = r;
        }
        __syncthreads();   // protect sred reuse next rep
    }
}

extern "C" void kernel_launch(void* const* d_in, const int* in_sizes, int n_in,
                              void* d_out, int out_size, void* d_ws, size_t ws_size,
                              hipStream_t stream)
{
    const float* word  = (const float*)d_in[0];
    const int*   nbr   = (const int*)  d_in[1];
    const float* mask  = (const float*)d_in[2];
    const float* W_enc = (const float*)d_in[3];
    const float* b_enc = (const float*)d_in[4];
    const float* W2    = (const float*)d_in[5];
    float* out = (float*)d_out;

    unsigned short* Xb    = (unsigned short*)d_ws;          // [32768][128] bf16, 8 MB
    unsigned short* Yb    = Xb + (size_t)R_TOT * EMB;       // 8 MB
    unsigned short* Xp    = Yb + (size_t)R_TOT * EMB;       // probe dummy, 8 MB
    unsigned short* Yp    = Xp + (size_t)R_TOT * EMB;       // probe dummy, 8 MB
    float*          dummy = (float*)(Yp + (size_t)R_TOT * EMB); // probe dummy, 512 KB

    dual_gemm     <<<R_TOT / 64, 256, 0, stream>>>(word, W_enc, b_enc, Xb, Yb, out);
    probe_dual    <<<R_TOT / 64, 256, 0, stream>>>(word, W_enc, b_enc, Xp, Yp);
    probe_gather  <<<B_SZ * 16,  256, 0, stream>>>(Xb, Yb, nbr, mask, W2, dummy);
    gather_pool_w2<<<B_SZ * 16,  256, 0, stream>>>(Xb, Yb, nbr, mask, W2, out);
}

// Round 12
// 32.701 us; speedup vs baseline: 10.5380x; 10.5380x over previous
//
#include <hip/hip_runtime.h>
#include <hip/hip_bf16.h>

#define B_SZ  64
#define N_SZ  512
#define K_SZ  16
#define EMB   128
#define R_TOT (B_SZ * N_SZ)   // 32768 rows

typedef __attribute__((ext_vector_type(8))) short bf16x8;
typedef __attribute__((ext_vector_type(4))) float f32x4;

// XOR-swizzled u16 index into a [*][128]-u16 LDS tile (16B-unit granularity).
#define SWZ(row, col) ((((row) << 7)) + ((((col) >> 3) ^ ((row) & 15)) << 3) + ((col) & 7))

static __device__ __forceinline__ unsigned short f2bf(float x) {
    __hip_bfloat16 h = __float2bfloat16(x);   // RNE
    return *reinterpret_cast<unsigned short*>(&h);
}
// bf16 pair unpack from a u32 (lo = bits 15:0, hi = bits 31:16), 1 VALU each
static __device__ __forceinline__ float bf_lo(unsigned int v) {
    union { unsigned int u; float f; } c; c.u = v << 16; return c.f;
}
static __device__ __forceinline__ float bf_hi(unsigned int v) {
    union { unsigned int u; float f; } c; c.u = v & 0xFFFF0000u; return c.f;
}

// Fused: X = word@Wtop + bias (store bf16, pre-relu); Y = relu(X)@Wbot (store bf16).
// B-fragments built directly from W_enc via coalesced per-lane scalar loads.
// bfr2 is loaded AFTER the mid-kernel barrier (not prefetched) to cut held VGPRs;
// __launch_bounds__(256,3) caps VGPR at ~170 -> 3 waves/SIMD (was 212 -> 2).
// First 32 blocks zero d_out. XCD-affine map: batch b's blocks on XCD b&7.
__global__ __launch_bounds__(256, 3) void dual_gemm(const float* __restrict__ word,
                                                    const float* __restrict__ W_enc,
                                                    const float* __restrict__ bias,
                                                    unsigned short* __restrict__ Xb,
                                                    unsigned short* __restrict__ Yb,
                                                    float* __restrict__ out)
{
    __shared__ unsigned short sA0[64 * EMB];   // 16 KB, bf16(word) tile, swizzled
    __shared__ unsigned short sA1[64 * EMB];   // 16 KB, relu(X) tile, swizzled
    const int tid = threadIdx.x;

    const int bid    = blockIdx.x;
    const int xcd    = bid & 7;
    const int j      = bid >> 3;
    const int b      = xcd + 8 * (j & 7);
    const int rchunk = j >> 3;
    const int block_row = b * N_SZ + rchunk * 64;

    if (bid < 32) out[bid * 256 + tid] = 0.f;

    for (int i = tid; i < 2048; i += 256) {
        int r = i >> 5, c4 = i & 31;
        float4 v = ((const float4*)(word + (size_t)(block_row + r) * EMB))[c4];
        unsigned short o[4] = { f2bf(v.x), f2bf(v.y), f2bf(v.z), f2bf(v.w) };
        *(uint2*)&sA0[SWZ(r, c4 * 4)] = *(uint2*)o;
    }

    const int lane  = tid & 63;
    const int w     = tid >> 6;
    const int l15   = lane & 15;
    const int g     = lane >> 4;
    const int ncol0 = w * 32;

    // B fragments for GEMM1 straight from W_enc (coalesced 64B segments per instr)
    bf16x8 bfr[2][4];
    #pragma unroll
    for (int nb = 0; nb < 2; ++nb) {
        const int col = ncol0 + nb * 16 + l15;
        #pragma unroll
        for (int ks = 0; ks < 4; ++ks) {
            unsigned short t[8];
            #pragma unroll
            for (int jj = 0; jj < 8; ++jj)
                t[jj] = f2bf(W_enc[(size_t)(ks * 32 + g * 8 + jj) * EMB + col]);
            bfr[nb][ks] = *(bf16x8*)t;
        }
    }

    f32x4 acc[4][2];
    #pragma unroll
    for (int mb = 0; mb < 4; ++mb)
        #pragma unroll
        for (int nb = 0; nb < 2; ++nb)
            acc[mb][nb] = (f32x4){0.f, 0.f, 0.f, 0.f};

    __syncthreads();

    // ---- GEMM1: sA0 @ Wtop ----
    #pragma unroll
    for (int ks = 0; ks < 4; ++ks) {
        bf16x8 a[4];
        #pragma unroll
        for (int mb = 0; mb < 4; ++mb)
            a[mb] = *(const bf16x8*)&sA0[SWZ(mb * 16 + l15, ks * 32 + g * 8)];
        #pragma unroll
        for (int mb = 0; mb < 4; ++mb)
            #pragma unroll
            for (int nb = 0; nb < 2; ++nb)
                acc[mb][nb] = __builtin_amdgcn_mfma_f32_16x16x32_bf16(a[mb], bfr[nb][ks], acc[mb][nb], 0, 0, 0);
    }

    // epilogue 1: X = acc + bias; store Xb (pre-relu); relu into sA1
    #pragma unroll
    for (int mb = 0; mb < 4; ++mb) {
        #pragma unroll
        for (int nb = 0; nb < 2; ++nb) {
            const int col = ncol0 + nb * 16 + l15;
            const float bv = bias[col];
            #pragma unroll
            for (int r = 0; r < 4; ++r) {
                const int row_l = mb * 16 + g * 4 + r;
                float x = acc[mb][nb][r] + bv;
                Xb[(size_t)(block_row + row_l) * EMB + col] = f2bf(x);
                sA1[SWZ(row_l, col)] = f2bf(fmaxf(x, 0.f));
            }
            acc[mb][nb] = (f32x4){0.f, 0.f, 0.f, 0.f};
        }
    }
    __syncthreads();

    // B fragments for GEMM2 (Wbot, L2-hot) — loaded here, not prefetched, to cut VGPR
    bf16x8 bfr2[2][4];
    #pragma unroll
    for (int nb = 0; nb < 2; ++nb) {
        const int col = ncol0 + nb * 16 + l15;
        #pragma unroll
        for (int ks = 0; ks < 4; ++ks) {
            unsigned short t[8];
            #pragma unroll
            for (int jj = 0; jj < 8; ++jj)
                t[jj] = f2bf(W_enc[(size_t)(128 + ks * 32 + g * 8 + jj) * EMB + col]);
            bfr2[nb][ks] = *(bf16x8*)t;
        }
    }

    // ---- GEMM2: relu(X) @ Wbot ----
    #pragma unroll
    for (int ks = 0; ks < 4; ++ks) {
        bf16x8 a[4];
        #pragma unroll
        for (int mb = 0; mb < 4; ++mb)
            a[mb] = *(const bf16x8*)&sA1[SWZ(mb * 16 + l15, ks * 32 + g * 8)];
        #pragma unroll
        for (int mb = 0; mb < 4; ++mb)
            #pragma unroll
            for (int nb = 0; nb < 2; ++nb)
                acc[mb][nb] = __builtin_amdgcn_mfma_f32_16x16x32_bf16(a[mb], bfr2[nb][ks], acc[mb][nb], 0, 0, 0);
    }
    #pragma unroll
    for (int mb = 0; mb < 4; ++mb)
        #pragma unroll
        for (int nb = 0; nb < 2; ++nb) {
            const int col = ncol0 + nb * 16 + l15;
            #pragma unroll
            for (int r = 0; r < 4; ++r) {
                const int row_l = mb * 16 + g * 4 + r;
                Yb[(size_t)(block_row + row_l) * EMB + col] = f2bf(acc[mb][nb][r]);
            }
        }
}

// Per (b,chunk): group g (one wave) sums mask*relu(X + mean_k Y[nb]) over 8 n's.
// All gather addressing is 32-bit offsets from wave-uniform SGPR bases (saddr-form
// loads, 1 VALU addr each); bf16 unpack via shl/and bitcasts; even/odd split
// accumulators break the dependent-add chain. In-block reduce -> chunk_pool,
// chunk_pool@W2 -> atomicAdd into out[b]. Batch b on XCD b&7.
__global__ __launch_bounds__(256) void gather_pool_w2(const unsigned short* __restrict__ Xb,
                                                      const unsigned short* __restrict__ Yb,
                                                      const int*   __restrict__ nbr,
                                                      const float* __restrict__ mask,
                                                      const float* __restrict__ W2,
                                                      float* __restrict__ out)
{
    const int bid   = blockIdx.x;
    const int xcd   = bid & 7;
    const int rest  = bid >> 3;
    const int chunk = rest & 15;
    const int b     = (rest >> 4) * 8 + xcd;
    const int g     = threadIdx.x >> 6;        // 4 groups = 4 waves
    const int lane  = threadIdx.x & 63;

    const unsigned int* Yw = (const unsigned int*)(Yb + (size_t)b * N_SZ * EMB); // uniform
    const unsigned int* Xw = (const unsigned int*)Xb;                            // uniform

    float s0 = 0.f, s1 = 0.f;
    for (int nn = 0; nn < 8; ++nn) {
        const int n = chunk * 32 + g * 8 + nn;                // wave-uniform
        const unsigned int base = (unsigned int)(b * N_SZ + n);
        const int* idx = nbr + (size_t)base * K_SZ;
        int id[K_SZ];
        #pragma unroll
        for (int k = 0; k < K_SZ; ++k) id[k] = idx[k];

        float a0a = 0.f, a0b = 0.f, a1a = 0.f, a1b = 0.f;
        #pragma unroll
        for (int k = 0; k < K_SZ; k += 2) {
            unsigned int v0 = Yw[(((unsigned int)id[k])     << 6) + lane];
            unsigned int v1 = Yw[(((unsigned int)id[k + 1]) << 6) + lane];
            a0a += bf_lo(v0); a1a += bf_hi(v0);
            a0b += bf_lo(v1); a1b += bf_hi(v1);
        }
        unsigned int xv = Xw[(base << 6) + lane];
        const float m = mask[base];
        s0 += fmaxf(bf_lo(xv) + (a0a + a0b) * 0.0625f, 0.f) * m;
        s1 += fmaxf(bf_hi(xv) + (a1a + a1b) * 0.0625f, 0.f) * m;
    }

    // in-block reduce: 4 wave-partials -> chunk_pool[128] in sred[0][*]
    __shared__ float sred[4][EMB];
    const int e0 = lane * 2;
    sred[g][e0]     = s0;
    sred[g][e0 + 1] = s1;
    __syncthreads();
    const int t = threadIdx.x;
    if (t < EMB)
        sred[0][t] = sred[0][t] + sred[1][t] + sred[2][t] + sred[3][t];
    __syncthreads();

    // chunk_pool @ W2 -> atomicAdd into out[b][*]
    if (t < EMB) {
        float r = 0.f;
        #pragma unroll 8
        for (int f = 0; f < EMB; ++f) r += sred[0][f] * W2[f * EMB + t];
        atomicAdd(&out[b * EMB + t], r);
    }
}

extern "C" void kernel_launch(void* const* d_in, const int* in_sizes, int n_in,
                              void* d_out, int out_size, void* d_ws, size_t ws_size,
                              hipStream_t stream)
{
    const float* word  = (const float*)d_in[0];
    const int*   nbr   = (const int*)  d_in[1];
    const float* mask  = (const float*)d_in[2];
    const float* W_enc = (const float*)d_in[3];
    const float* b_enc = (const float*)d_in[4];
    const float* W2    = (const float*)d_in[5];
    float* out = (float*)d_out;

    unsigned short* Xb = (unsigned short*)d_ws;          // [32768][128] bf16, 8 MB
    unsigned short* Yb = Xb + (size_t)R_TOT * EMB;       // 8 MB

    dual_gemm     <<<R_TOT / 64, 256, 0, stream>>>(word, W_enc, b_enc, Xb, Yb, out);
    gather_pool_w2<<<B_SZ * 16,  256, 0, stream>>>(Xb, Yb, nbr, mask, W2, out);
}